// Round 3
// baseline (667.130 us; speedup 1.0000x reference)
//
#include <hip/hip_runtime.h>
#include <cfloat>

#define BATCH 4
#define P 8192
#define C 64
#define KNN 16
#define NPTS (BATCH * P)        // 32768
#define NEDGE (NPTS * KNN)      // 524288
#define EPSV 1e-5f
#define SLOPE 0.2f
#define NQ 2                    // column-range split per row-tile
#define QCOLS (P / NQ)          // 4096 cols per block
#define NCH (QCOLS / 64)        // 64 chunks
#define CAP 48                  // append slots per row per generation (mean ~16, +8 sigma)

typedef __attribute__((ext_vector_type(8))) short bf16x8;
typedef __attribute__((ext_vector_type(16))) float f32x16;

// ---------------- workspace layout (float element offsets) ----------------
// U      : [NPTS][C]   @ 0          (2097152)   written AFTER knn
// V      : [NPTS][C]   @ 2097152    (2097152)   written AFTER knn
// xfh/xfm/xfl bf16 frags alias U/V region (dead after knn)
// sq     : [NPTS]      @ 4194304    (32768)
// stats  : [128]       @ 4227072
// sshift : [128]       @ 4227200
// idx    : int[NEDGE]  @ 4227328    (524288)
// pv     : [NPTS][NQ][16] float @ 4751616 (1048576)
// pi     : [NPTS][NQ][16] int   @ 5800192 (1048576)
// total = 6848768 floats = 26.1 MB

__device__ __forceinline__ unsigned short f2bf(float f) {
    unsigned u = __float_as_uint(f);
    u += 0x7FFFu + ((u >> 16) & 1u);
    return (unsigned short)(u >> 16);
}
__device__ __forceinline__ float bf2f(unsigned short s) {
    return __uint_as_float(((unsigned)s) << 16);
}
// monotone float<->uint map: monof(a) < monof(b)  <=>  a < b (finite floats)
__device__ __forceinline__ unsigned monof(float f) {
    unsigned u = __float_as_uint(f);
    return u ^ ((unsigned)((int)u >> 31) | 0x80000000u);
}
__device__ __forceinline__ float invmonof(unsigned k) {
    unsigned u = (k & 0x80000000u) ? (k ^ 0x80000000u) : ~k;
    return __uint_as_float(u);
}

// ---------------------------------------------------------------------------
// K0: fragment-layout 3-way bf16 split of x + exact fp32 row norms.
// ---------------------------------------------------------------------------
__global__ void prep_frag(const float* __restrict__ x, uint4* __restrict__ xfh,
                          uint4* __restrict__ xfm, uint4* __restrict__ xfl,
                          float* __restrict__ sq) {
    __shared__ float part[32][9];
    int tid = threadIdx.x;
    int ptl = tid >> 3, j8 = tid & 7;
    int g = blockIdx.x;
    int p = g * 32 + ptl;
    const float4* xp = (const float4*)(x + (size_t)p * C + j8 * 8);
    float4 a = xp[0], b = xp[1];
    float v[8] = {a.x, a.y, a.z, a.w, b.x, b.y, b.z, b.w};
    unsigned short hs[8], ms[8], ls[8];
    float ssum = 0.f;
#pragma unroll
    for (int e = 0; e < 8; ++e) {
        float xv = v[e];
        ssum = fmaf(xv, xv, ssum);
        unsigned short h = f2bf(xv);
        float r1 = xv - bf2f(h);
        unsigned short m = f2bf(r1);
        float r2 = r1 - bf2f(m);
        unsigned short l = f2bf(r2);
        hs[e] = h; ms[e] = m; ls[e] = l;
    }
    int dst = (g * 4 + (j8 >> 1)) * 64 + ptl + 32 * (j8 & 1);
    uint4 ph, pm, pl;
    ph.x = (unsigned)hs[0] | ((unsigned)hs[1] << 16);
    ph.y = (unsigned)hs[2] | ((unsigned)hs[3] << 16);
    ph.z = (unsigned)hs[4] | ((unsigned)hs[5] << 16);
    ph.w = (unsigned)hs[6] | ((unsigned)hs[7] << 16);
    pm.x = (unsigned)ms[0] | ((unsigned)ms[1] << 16);
    pm.y = (unsigned)ms[2] | ((unsigned)ms[3] << 16);
    pm.z = (unsigned)ms[4] | ((unsigned)ms[5] << 16);
    pm.w = (unsigned)ms[6] | ((unsigned)ms[7] << 16);
    pl.x = (unsigned)ls[0] | ((unsigned)ls[1] << 16);
    pl.y = (unsigned)ls[2] | ((unsigned)ls[3] << 16);
    pl.z = (unsigned)ls[4] | ((unsigned)ls[5] << 16);
    pl.w = (unsigned)ls[6] | ((unsigned)ls[7] << 16);
    xfh[dst] = ph; xfm[dst] = pm; xfl[dst] = pl;
    part[ptl][j8] = ssum;
    __syncthreads();
    if (j8 == 0) {
        float s = 0.f;
#pragma unroll
        for (int k = 0; k < 8; ++k) s += part[ptl][k];
        sq[p] = s;
    }
}

// ---------------------------------------------------------------------------
// K1: KNN, generation-batched rank selection, r9.
//
// r8 post-mortem: dur 477us with MfmaUtil 18.6 / VALUBusy 39 / HBM 2% —
// latency-serialized, and the only serial-by-construction structure was the
// reselect's dynamic-trip loop (`for j<n` over bufk: ds_read_b64 +
// lgkmcnt(0) + cmp per iter, ~64cy each, ~1000 per wave).
//
// r9 changes (structure otherwise = r8):
//  * FIXED-SHAPE reselect: CAP=48, all slots are valid keys; unused slots
//    hold sentinel ~0ull (rank >= 16 always, never selected; equal
//    sentinels harmless since their ranks are >= 16). Rank = 32x unrolled
//    ds_read_b128 (2 keys each, broadcast, conflict-free, independent)
//    + 64 u64 compares. Zero dynamic trip counts. Sentinel-clear after
//    ranking (wave-lockstep: all reads precede the clear; rows are
//    wave-private so no cross-wave race).
//  * per-kk B-fragment loads inside the unrolled kk loop: live B regs
//    48 -> ~12-24; loads overlap the previous kk's MFMAs.
//  * __launch_bounds__(256,3): unified reg cap ~170 so A(48)+B(24)+acc(32)
//    +misc fits with no spill/AGPR-shuffle (r8 allocated only 64 VGPRs for
//    ~130 live values). Costs 1 block/CU occupancy; buys clean codegen.
// LDS = 24576 + 8192 + 256 + 256 = 33280 B.
// ---------------------------------------------------------------------------
__global__ __launch_bounds__(256, 3) void knn_kernel(const uint4* __restrict__ xfh,
                                                     const uint4* __restrict__ xfm,
                                                     const uint4* __restrict__ xfl,
                                                     const float* __restrict__ sq,
                                                     float* __restrict__ pv,
                                                     int* __restrict__ pi) {
    __shared__ unsigned long long bufk[64 * CAP];  // append buffer (keys; sentinel-padded)
    __shared__ unsigned long long topk[64 * 16];   // current top-16 keys, rank-ordered
    __shared__ float worstL[64];
    __shared__ int   cnt[64];

    int tid = threadIdx.x;
    int b = blockIdx.x & 3;              // batch -> XCDs {b, b+4}: frags L2-resident
    int t = blockIdx.x >> 2;
    int tile = t & 127;
    int half = t >> 7;
    int bglob = b * P;
    int r0 = tile * 64;
    int colbase = half * QCOLS;
    int w = tid >> 6, lane = tid & 63;
    int wr = w & 1, wc = w >> 1;

    if (tid < 64) cnt[tid] = 0;

    // persistent A fragments for this wave's 32 rows
    int gA = ((bglob + r0) >> 5) + wr;
    bf16x8 Ah[4], Am[4], Al[4];
#pragma unroll
    for (int kk = 0; kk < 4; ++kk) {
        Ah[kk] = __builtin_bit_cast(bf16x8, xfh[(gA * 4 + kk) * 64 + lane]);
        Am[kk] = __builtin_bit_cast(bf16x8, xfm[(gA * 4 + kk) * 64 + lane]);
        Al[kk] = __builtin_bit_cast(bf16x8, xfl[(gA * 4 + kk) * 64 + lane]);
    }

    int rbase = wr * 32 + 4 * (lane >> 5);   // row of reg: rbase+(reg&3)+8*(reg>>2)
    int colq = wc * 32 + (lane & 31);        // this lane's column within chunk

    for (int chunk = 0; chunk < NCH; ++chunk) {
        int c0 = colbase + chunk * 64;
        int gB = ((bglob + c0) >> 5) + wc;
        float sc = sq[bglob + c0 + colq];

        f32x16 acc0, acc1;
#pragma unroll
        for (int i = 0; i < 16; ++i) { acc0[i] = 0.f; acc1[i] = 0.f; }
        const uint4* bh = &xfh[(gB * 4) * 64 + lane];
        const uint4* bm = &xfm[(gB * 4) * 64 + lane];
        const uint4* bl = &xfl[(gB * 4) * 64 + lane];
#pragma unroll
        for (int kk = 0; kk < 4; ++kk) {
            bf16x8 Bh = __builtin_bit_cast(bf16x8, bh[kk * 64]);
            bf16x8 Bm = __builtin_bit_cast(bf16x8, bm[kk * 64]);
            bf16x8 Bl = __builtin_bit_cast(bf16x8, bl[kk * 64]);
            acc0 = __builtin_amdgcn_mfma_f32_32x32x16_bf16(Ah[kk], Bh, acc0, 0, 0, 0);
            acc1 = __builtin_amdgcn_mfma_f32_32x32x16_bf16(Ah[kk], Bm, acc1, 0, 0, 0);
            acc0 = __builtin_amdgcn_mfma_f32_32x32x16_bf16(Am[kk], Bh, acc0, 0, 0, 0);
            acc1 = __builtin_amdgcn_mfma_f32_32x32x16_bf16(Am[kk], Bm, acc1, 0, 0, 0);
            acc0 = __builtin_amdgcn_mfma_f32_32x32x16_bf16(Ah[kk], Bl, acc0, 0, 0, 0);
            acc1 = __builtin_amdgcn_mfma_f32_32x32x16_bf16(Al[kk], Bh, acc1, 0, 0, 0);
        }

        int colg = bglob + c0 + colq;
        if (chunk == 0) {
            // bootstrap: slot the 64 chunk-0 scores directly as 16 top + 48 buf
#pragma unroll
            for (int reg = 0; reg < 16; ++reg) {
                float s = fmaf(-2.f, acc0[reg] + acc1[reg], sc);
                int row = rbase + (reg & 3) + 8 * (reg >> 2);
                unsigned long long key =
                    ((unsigned long long)monof(s) << 32) | (unsigned)colg;
                if (colq < 16) topk[row * 16 + colq] = key;
                else           bufk[row * CAP + (colq - 16)] = key;
            }
        } else {
            // thresholds for this wave's 16 distinct rows (broadcast b128 reads;
            // worstL is stable within a generation)
            float4 twA[4];
#pragma unroll
            for (int g4 = 0; g4 < 4; ++g4)
                twA[g4] = *(const float4*)&worstL[rbase + 8 * g4];
#pragma unroll
            for (int reg = 0; reg < 16; ++reg) {
                float s = fmaf(-2.f, acc0[reg] + acc1[reg], sc);
                float tW = ((const float*)&twA[reg >> 2])[reg & 3];
                if (s < tW) {
                    int row = rbase + (reg & 3) + 8 * (reg >> 2);
                    int slot = atomicAdd(&cnt[row], 1);
                    if (slot < CAP)
                        bufk[row * CAP + slot] =
                            ((unsigned long long)monof(s) << 32) | (unsigned)colg;
                }
            }
        }

        // ---- generation boundary: rank-based reselect (chunks 0,1,3,7,15,31,63)
        // Fixed shape: every lane owns one of the 64 union slots; rank over all
        // 64 keys via 32 unrolled b128 broadcast reads (pipelined, conflict-free).
        if ((chunk & (chunk + 1)) == 0) {
            __syncthreads();   // appends visible
            for (int rr = 0; rr < 16; ++rr) {
                int row = w * 16 + rr;
                unsigned long long mykey = (lane < 16)
                    ? topk[row * 16 + lane]
                    : bufk[row * CAP + (lane - 16)];
                int rank = 0;
                const uint4* tk = (const uint4*)&topk[row * 16];
#pragma unroll
                for (int j = 0; j < 8; ++j) {
                    uint4 q = tk[j];
                    rank += ((((unsigned long long)q.y << 32) | q.x) < mykey) ? 1 : 0;
                    rank += ((((unsigned long long)q.w << 32) | q.z) < mykey) ? 1 : 0;
                }
                const uint4* bk = (const uint4*)&bufk[row * CAP];
#pragma unroll
                for (int j = 0; j < 24; ++j) {
                    uint4 q = bk[j];
                    rank += ((((unsigned long long)q.y << 32) | q.x) < mykey) ? 1 : 0;
                    rank += ((((unsigned long long)q.w << 32) | q.z) < mykey) ? 1 : 0;
                }
                // real keys distinct (id in low bits) => ranks distinct; exactly
                // 16 reals win; sentinels rank >= 16. Wave-lockstep: all reads
                // above retire before the writes below; rows are wave-private.
                if (rank < 16) topk[row * 16 + rank] = mykey;
                if (rank == 15) worstL[row] = invmonof((unsigned)(mykey >> 32));
                if (lane >= 16) bufk[row * CAP + (lane - 16)] = ~0ull;  // sentinel-clear
                if (lane == 0) cnt[row] = 0;
            }
            __syncthreads();   // topk/worstL stable, buffer free
        }
    }

    // ---- output: topk is rank-ordered; lanes 0-15 write each owned row ----
    for (int rr = 0; rr < 16; ++rr) {
        int row = w * 16 + rr;
        if (lane < 16) {
            unsigned long long k = topk[row * 16 + lane];
            size_t o = (((size_t)(bglob + r0 + row)) * NQ + half) * KNN;
            pv[o + lane] = invmonof((unsigned)(k >> 32));
            pi[o + lane] = (int)(unsigned)(k & 0xFFFFFFFFu);
        }
    }
}

// ---------------------------------------------------------------------------
// K1b: merge NQ=2 partial top-16 lists per row -> final idx.
// ---------------------------------------------------------------------------
__global__ void merge_kernel(const float* __restrict__ pv, const int* __restrict__ pi,
                             int* __restrict__ idx_out) {
    __shared__ float mv[128 * 33];
    __shared__ int   mi[128 * 33];
    int tid = threadIdx.x;
    int lr = tid & 127, q = tid >> 7;
    int row = blockIdx.x * 128 + lr;
    size_t o = ((size_t)row * NQ + q) * KNN;
#pragma unroll
    for (int j = 0; j < 16; ++j) {
        mv[lr * 33 + q * 16 + j] = pv[o + j];
        mi[lr * 33 + q * 16 + j] = pi[o + j];
    }
    __syncthreads();
    if (tid < 128) {
        float tv[16];
        int ti[16];
        float worst = FLT_MAX;
#pragma unroll
        for (int j = 0; j < 16; ++j) { tv[j] = FLT_MAX; ti[j] = 0; }
        for (int e = 0; e < 32; ++e) {
            float s = mv[tid * 33 + e];
            if (s < worst) {
                float mx = tv[0];
                int pos = 0;
#pragma unroll
                for (int j = 1; j < 16; ++j) {
                    bool g = tv[j] > mx;
                    mx = g ? tv[j] : mx;
                    pos = g ? j : pos;
                }
#pragma unroll
                for (int j = 0; j < 16; ++j)
                    if (j == pos) { tv[j] = s; ti[j] = mi[tid * 33 + e]; }
                float nw = tv[0];
#pragma unroll
                for (int j = 1; j < 16; ++j) nw = fmaxf(nw, tv[j]);
                worst = nw;
            }
        }
        size_t oo = (size_t)row * KNN;
#pragma unroll
        for (int j = 0; j < 16; ++j) idx_out[oo + j] = ti[j];
    }
}

// ---------------------------------------------------------------------------
// K2: U = x @ (W1 - W2), V = x @ W2
// ---------------------------------------------------------------------------
__global__ void prep_UV(const float* __restrict__ x, const float* __restrict__ W,
                        float* __restrict__ U, float* __restrict__ V) {
    __shared__ float Ws[128][64];
    __shared__ float xs[4][64];
    int tid = threadIdx.x;
    for (int i = tid; i < 128 * 64; i += 256) ((float*)Ws)[i] = W[i];
    int p0 = blockIdx.x * 4;
    int r = tid >> 6, c = tid & 63;
    xs[r][c] = x[(size_t)(p0 + r) * C + c];
    __syncthreads();
    float u = 0.f, v = 0.f;
#pragma unroll
    for (int k = 0; k < 64; ++k) {
        float xv = xs[r][k];
        float w1 = Ws[k][c];
        float w2 = Ws[64 + k][c];
        u = fmaf(xv, w1 - w2, u);
        v = fmaf(xv, w2, v);
    }
    size_t o = (size_t)(p0 + r) * C + c;
    U[o] = u;
    V[o] = v;
}

// ---------------------------------------------------------------------------
// K3: BN stats
// ---------------------------------------------------------------------------
__global__ void stats_kernel(const float* __restrict__ U, const float* __restrict__ V,
                             const float* __restrict__ bias, const int* __restrict__ idx,
                             float* __restrict__ stats) {
    int tid = threadIdx.x;
    int c = tid & 63, kk = tid >> 6;
    int p0 = blockIdx.x * 32;
    float bc = bias[c];
    float sum = 0.f, sumsq = 0.f;
    for (int pp = 0; pp < 32; ++pp) {
        int p = p0 + pp;
        float u = U[(size_t)p * C + c] + bc;
#pragma unroll
        for (int k4 = 0; k4 < 4; ++k4) {
            int j = idx[(size_t)p * KNN + kk * 4 + k4];
            float h = u + V[(size_t)j * C + c];
            sum += h;
            sumsq = fmaf(h, h, sumsq);
        }
    }
    __shared__ float red[2][4][64];
    red[0][kk][c] = sum;
    red[1][kk][c] = sumsq;
    __syncthreads();
    if (tid < 64) {
        float s = red[0][0][tid] + red[0][1][tid] + red[0][2][tid] + red[0][3][tid];
        atomicAdd(&stats[tid], s);
    } else if (tid < 128) {
        int cc = tid - 64;
        float s = red[1][0][cc] + red[1][1][cc] + red[1][2][cc] + red[1][3][cc];
        atomicAdd(&stats[64 + cc], s);
    }
}

__global__ void finalize_kernel(const float* __restrict__ stats,
                                const float* __restrict__ gamma,
                                const float* __restrict__ beta,
                                float* __restrict__ sshift) {
    int c = threadIdx.x;
    const float N = (float)NEDGE;
    float mean = stats[c] / N;
    float var = stats[64 + c] / N - mean * mean;
    float s = gamma[c] * rsqrtf(var + EPSV);
    sshift[c] = s;
    sshift[64 + c] = beta[c] - mean * s;
}

// ---------------------------------------------------------------------------
// K5: out = lrelu(s*(U+b + max/min_k V[idx]) + t)  (monotone fusion of max_k)
// ---------------------------------------------------------------------------
__global__ void out_kernel(const float* __restrict__ U, const float* __restrict__ V,
                           const float* __restrict__ bias, const int* __restrict__ idx,
                           const float* __restrict__ sshift, float* __restrict__ out) {
    int tid = threadIdx.x;
    int c = tid & 63, g = tid >> 6;
    int p0 = blockIdx.x * 16;
    float s = sshift[c], t = sshift[64 + c];
    float bc = bias[c];
    for (int pp = g; pp < 16; pp += 4) {
        int p = p0 + pp;
        float mx = -FLT_MAX, mn = FLT_MAX;
#pragma unroll
        for (int k = 0; k < KNN; ++k) {
            int j = idx[(size_t)p * KNN + k];
            float v = V[(size_t)j * C + c];
            mx = fmaxf(mx, v);
            mn = fminf(mn, v);
        }
        float hsel = (s >= 0.f) ? mx : mn;
        float hn = fmaf(s, U[(size_t)p * C + c] + bc + hsel, t);
        out[(size_t)p * C + c] = (hn >= 0.f) ? hn : SLOPE * hn;
    }
}

// ---------------------------------------------------------------------------
extern "C" void kernel_launch(void* const* d_in, const int* in_sizes, int n_in,
                              void* d_out, int out_size, void* d_ws, size_t ws_size,
                              hipStream_t stream) {
    const float* x     = (const float*)d_in[0];
    const float* W     = (const float*)d_in[2];
    const float* bias  = (const float*)d_in[3];
    const float* gamma = (const float*)d_in[4];
    const float* beta  = (const float*)d_in[5];
    float* out = (float*)d_out;

    float* wsf    = (float*)d_ws;
    float* U      = wsf;
    float* V      = wsf + 2097152;
    uint4* xfh    = (uint4*)wsf;                   // aliases U/V, dead after knn
    uint4* xfm    = (uint4*)(wsf + 1048576);
    uint4* xfl    = (uint4*)(wsf + 2097152);
    float* sq     = wsf + 4194304;
    float* stats  = wsf + 4227072;
    float* sshift = wsf + 4227200;
    int*   idx    = (int*)(wsf + 4227328);
    float* pv     = wsf + 4751616;
    int*   pi     = (int*)(wsf + 5800192);

    hipLaunchKernelGGL(prep_frag, dim3(NPTS / 32), dim3(256), 0, stream, x, xfh, xfm, xfl, sq);
    hipLaunchKernelGGL(knn_kernel, dim3(BATCH * (P / 64) * NQ), dim3(256), 0, stream,
                       (const uint4*)xfh, (const uint4*)xfm, (const uint4*)xfl, sq, pv, pi);
    hipLaunchKernelGGL(merge_kernel, dim3(NPTS / 128), dim3(256), 0, stream, pv, pi, idx);
    hipLaunchKernelGGL(prep_UV, dim3(NPTS / 4), dim3(256), 0, stream, x, W, U, V);
    hipMemsetAsync(stats, 0, 128 * sizeof(float), stream);
    hipLaunchKernelGGL(stats_kernel, dim3(NPTS / 32), dim3(256), 0, stream, U, V, bias, idx, stats);
    hipLaunchKernelGGL(finalize_kernel, dim3(1), dim3(64), 0, stream, stats, gamma, beta, sshift);
    hipLaunchKernelGGL(out_kernel, dim3(NPTS / 16), dim3(256), 0, stream, U, V, bias, idx, sshift, out);
}